// Round 7
// baseline (103.437 us; speedup 1.0000x reference)
//
#include <hip/hip_runtime.h>
#include <hip/hip_bf16.h>

typedef short bf16x8 __attribute__((ext_vector_type(8)));
typedef short bf16x4 __attribute__((ext_vector_type(4)));
typedef float f32x4  __attribute__((ext_vector_type(4)));

__device__ __forceinline__ unsigned short f2bf(float f) {
    union { float fv; unsigned int u; } v; v.fv = f;
    unsigned int r = v.u + 0x7FFFu + ((v.u >> 16) & 1u);
    return (unsigned short)(r >> 16);
}

__device__ __forceinline__ short f2bf_n(float f) {
    union { __hip_bfloat16 h; short s; } u;
    u.h = __float2bfloat16(f);
    return u.s;
}

__device__ __forceinline__ void gload16(const short* g, short* l) {
    __builtin_amdgcn_global_load_lds(
        (const __attribute__((address_space(1))) void*)g,
        (__attribute__((address_space(3))) void*)l, 16, 0, 0);
}

// ---- convert x f32 -> bf16, 8 elems/thread ----
__global__ __launch_bounds__(256) void cvt_x(
    const float* __restrict__ x, short* __restrict__ xb)
{
    size_t i = ((size_t)blockIdx.x * 256 + threadIdx.x) * 8;
    f32x4 a = *(const f32x4*)(x + i);
    f32x4 b = *(const f32x4*)(x + i + 4);
    bf16x8 s;
    #pragma unroll
    for (int e = 0; e < 4; ++e) { s[e] = (short)f2bf(a[e]); s[4 + e] = (short)f2bf(b[e]); }
    *(bf16x8*)(xb + i) = s;
}

// ---- tiled transpose: f32 [K][N] -> bf16 [N][K], 32x32 tiles ----
__global__ __launch_bounds__(256) void tr_w(
    const float* __restrict__ src, short* __restrict__ dst, int K, int N)
{
    __shared__ float tile[32][33];
    const int tx = threadIdx.x;
    const int nb = N >> 5;
    const int k0 = (blockIdx.x / nb) * 32;
    const int n0 = (blockIdx.x % nb) * 32;
    const int r  = tx >> 3;
    const int c4 = (tx & 7) * 4;
    f32x4 v = *(const f32x4*)(src + (size_t)(k0 + r) * N + n0 + c4);
    #pragma unroll
    for (int e = 0; e < 4; ++e) tile[r][c4 + e] = v[e];
    __syncthreads();
    bf16x4 o;
    #pragma unroll
    for (int e = 0; e < 4; ++e) o[e] = (short)f2bf(tile[c4 + e][r]);
    *(bf16x4*)(dst + (size_t)(n0 + r) * K + k0 + c4) = o;
}

// ---- GEMM: 128x128 tile, double-buffered LDS, counted vmcnt prefetch ----
template<int F32OUT>
__global__ __launch_bounds__(256, 2) void gemm_db(
    const short* __restrict__ A, const short* __restrict__ Bt,
    short* __restrict__ Cb, float* __restrict__ Cf, const float* __restrict__ bias,
    int M, int N, int K, int NB)
{
    __shared__ short lds[2][2][128 * 64];   // [buf][A|B][row*64+chunk*8]
    const int t    = threadIdx.x;
    const int lane = t & 63;
    const int wid  = t >> 6;
    const int l15  = lane & 15;
    const int lg   = lane >> 4;

    const int cpx = gridDim.x >> 3;
    const int swz = (blockIdx.x & 7) * cpx + (blockIdx.x >> 3);
    const int m0 = (swz / NB) * 128;
    const int n0 = (swz % NB) * 128;

    const int wm = (wid >> 1) * 64;
    const int wn = (wid & 1) * 64;

    const int scol = 8 * ((lane & 7) ^ ((lane >> 3) & 7));

    float bval[4];
    if constexpr (F32OUT) {
        #pragma unroll
        for (int ni = 0; ni < 4; ++ni) bval[ni] = bias[n0 + wn + ni * 16 + l15];
    }

    f32x4 acc[4][4];
    #pragma unroll
    for (int i = 0; i < 4; ++i)
        #pragma unroll
        for (int j = 0; j < 4; ++j)
            acc[i][j] = f32x4{0.f, 0.f, 0.f, 0.f};

    const int NT = K >> 6;

    auto stage = [&](int buf, int tk) {
        #pragma unroll
        for (int j = 0; j < 4; ++j) {
            const int r = wid * 32 + j * 8 + (lane >> 3);
            gload16(A  + (size_t)(m0 + r) * K + tk * 64 + scol,
                    &lds[buf][0][(wid * 32 + j * 8) * 64]);
            gload16(Bt + (size_t)(n0 + r) * K + tk * 64 + scol,
                    &lds[buf][1][(wid * 32 + j * 8) * 64]);
        }
    };

    stage(0, 0);

    for (int tk = 0; tk < NT; ++tk) {
        const int cur = tk & 1;
        if (tk + 1 < NT) {
            stage(cur ^ 1, tk + 1);
            asm volatile("s_waitcnt vmcnt(8)" ::: "memory");
        } else {
            asm volatile("s_waitcnt vmcnt(0)" ::: "memory");
        }
        __builtin_amdgcn_s_barrier();

        bf16x8 af[4][2], bg[4][2];
        #pragma unroll
        for (int kk = 0; kk < 2; ++kk) {
            #pragma unroll
            for (int mi = 0; mi < 4; ++mi)
                af[mi][kk] = *(const bf16x8*)&lds[cur][0][
                    (wm + mi * 16 + l15) * 64 + (((kk * 4 + lg) ^ (l15 & 7)) * 8)];
            #pragma unroll
            for (int ni = 0; ni < 4; ++ni)
                bg[ni][kk] = *(const bf16x8*)&lds[cur][1][
                    (wn + ni * 16 + l15) * 64 + (((kk * 4 + lg) ^ (l15 & 7)) * 8)];
        }

        __builtin_amdgcn_s_setprio(1);
        #pragma unroll
        for (int kk = 0; kk < 2; ++kk)
            #pragma unroll
            for (int mi = 0; mi < 4; ++mi)
                #pragma unroll
                for (int ni = 0; ni < 4; ++ni)
                    acc[mi][ni] = __builtin_amdgcn_mfma_f32_16x16x32_bf16(
                        af[mi][kk], bg[ni][kk], acc[mi][ni], 0, 0, 0);
        __builtin_amdgcn_s_setprio(0);
        __builtin_amdgcn_s_barrier();
    }

    #pragma unroll
    for (int mi = 0; mi < 4; ++mi) {
        #pragma unroll
        for (int ni = 0; ni < 4; ++ni) {
            const int col = n0 + wn + ni * 16 + l15;
            #pragma unroll
            for (int r = 0; r < 4; ++r) {
                const int rowi = m0 + wm + mi * 16 + 4 * lg + r;
                if constexpr (F32OUT) {
                    Cf[(size_t)rowi * N + col] = acc[mi][ni][r] + bval[ni];
                } else {
                    Cb[(size_t)rowi * N + col] = (short)f2bf(acc[mi][ni][r]);
                }
            }
        }
    }
}

// ---- fused attention: grid 1024; block = (qquarter, bp, h); 8 waves x 16 q-rows
// decode: pairid = bid & 255 (bp*8+h), qh = bid >> 8 (0..3) -> the 4 q-quarters
// of one (bp,h) land 256 apart = same XCD (K/V L2 sharing). 4 blocks/CU.
__global__ __launch_bounds__(512, 4) void attn_kernel(
    const short* __restrict__ qkv, short* __restrict__ attn_out)
{
    __shared__ short Kl[2][64][72];   // K tile  [kv][d]
    __shared__ short Vt[2][64][76];   // V^T tile [d][kv]
    const int t    = threadIdx.x;
    const int lane = t & 63;
    const int wid  = t >> 6;
    const int l15  = lane & 15;
    const int lg   = lane >> 4;
    const int pairid = blockIdx.x & 255;
    const int qh  = blockIdx.x >> 8;
    const int bp  = pairid >> 3;
    const int h   = pairid & 7;
    const size_t tok0 = (size_t)bp * 512;
    const int q0   = qh * 128 + wid * 16;
    const int qcol = h * 64;

    // Q fragment (B-operand layout): col m = l15, k(d) = kf*32 + 8*lg + e
    bf16x8 qf[2];
    #pragma unroll
    for (int kf = 0; kf < 2; ++kf)
        qf[kf] = *(const bf16x8*)(qkv + (tok0 + q0 + l15) * 1536
                                  + qcol + kf * 32 + 8 * lg);

    f32x4 ot[4];
    #pragma unroll
    for (int i = 0; i < 4; ++i) ot[i] = f32x4{0.f, 0.f, 0.f, 0.f};
    float mrun = -1e30f, lrun = 0.f;

    const int sn = t >> 3;         // 0..63 (kv row)
    const int sd = (t & 7) * 8;    // 0..56 (d octet)

    const short* kvbase = qkv + (tok0 + sn) * 1536 + qcol + sd;
    bf16x8 kreg = *(const bf16x8*)(kvbase + 512);
    bf16x8 vreg = *(const bf16x8*)(kvbase + 1024);

    const float C = 0.18033688011112042f;   // 0.125 * log2(e)

    for (int tkv = 0; tkv < 8; ++tkv) {
        const int cur = tkv & 1;
        *(bf16x8*)&Kl[cur][sn][sd] = kreg;
        #pragma unroll
        for (int i = 0; i < 8; ++i) Vt[cur][sd + i][sn] = vreg[i];
        if (tkv < 7) {
            const short* nxt = kvbase + (size_t)(tkv + 1) * 64 * 1536;
            kreg = *(const bf16x8*)(nxt + 512);
            vreg = *(const bf16x8*)(nxt + 1024);
        }
        __syncthreads();

        // S^T = K * Q^T  (col m = l15, row n = ni*16 + 4*lg + r), raw scores
        f32x4 st[4];
        #pragma unroll
        for (int i = 0; i < 4; ++i) st[i] = f32x4{0.f, 0.f, 0.f, 0.f};
        __builtin_amdgcn_s_setprio(1);
        #pragma unroll
        for (int kf = 0; kf < 2; ++kf) {
            #pragma unroll
            for (int ni = 0; ni < 4; ++ni) {
                bf16x8 kfr = *(const bf16x8*)&Kl[cur][ni * 16 + l15][kf * 32 + 8 * lg];
                st[ni] = __builtin_amdgcn_mfma_f32_16x16x32_bf16(
                    kfr, qf[kf], st[ni], 0, 0, 0);
            }
        }
        __builtin_amdgcn_s_setprio(0);

        // online softmax (log2 domain); fmax on raw, scale once; defer-max THR=8
        float pm = -1e30f;
        #pragma unroll
        for (int ni = 0; ni < 4; ++ni)
            #pragma unroll
            for (int r = 0; r < 4; ++r)
                pm = fmaxf(pm, st[ni][r]);
        pm = fmaxf(pm, __shfl_xor(pm, 16));
        pm = fmaxf(pm, __shfl_xor(pm, 32));
        pm *= C;
        if (!__all(pm <= mrun + 8.f)) {
            const float mnew = fmaxf(mrun, pm);
            const float fsc  = __builtin_amdgcn_exp2f(mrun - mnew);
            lrun *= fsc;
            #pragma unroll
            for (int di = 0; di < 4; ++di) ot[di] *= fsc;
            mrun = mnew;
        }
        float ps = 0.f;
        #pragma unroll
        for (int ni = 0; ni < 4; ++ni)
            #pragma unroll
            for (int r = 0; r < 4; ++r) {
                float e = __builtin_amdgcn_exp2f(__builtin_fmaf(st[ni][r], C, -mrun));
                st[ni][r] = e;
                ps += e;
            }
        ps += __shfl_xor(ps, 16);
        ps += __shfl_xor(ps, 32);
        lrun += ps;

        // O^T += V^T * P^T  (P^T D-frag is the 16x16x16 B-operand layout)
        __builtin_amdgcn_s_setprio(1);
        #pragma unroll
        for (int ni = 0; ni < 4; ++ni) {
            bf16x4 pb;
            #pragma unroll
            for (int r = 0; r < 4; ++r) pb[r] = f2bf_n(st[ni][r]);
            #pragma unroll
            for (int di = 0; di < 4; ++di) {
                bf16x4 av = *(const bf16x4*)&Vt[cur][di * 16 + l15][ni * 16 + 4 * lg];
                ot[di] = __builtin_amdgcn_mfma_f32_16x16x16bf16_1k(
                    av, pb, ot[di], 0, 0, 0);
            }
        }
        __builtin_amdgcn_s_setprio(0);
    }

    const float inv = 1.f / lrun;
    #pragma unroll
    for (int di = 0; di < 4; ++di) {
        const size_t tok = tok0 + q0 + l15;
        const int col = qcol + di * 16 + 4 * lg;
        bf16x4 o4;
        #pragma unroll
        for (int r = 0; r < 4; ++r)
            o4[r] = f2bf_n(ot[di][r] * inv);
        *(bf16x4*)(attn_out + tok * 512 + col) = o4;
    }
}

extern "C" void kernel_launch(void* const* d_in, const int* in_sizes, int n_in,
                              void* d_out, int out_size, void* d_ws, size_t ws_size,
                              hipStream_t stream) {
    const float* x    = (const float*)d_in[0];   // [16384][512]
    const float* Wqkv = (const float*)d_in[1];   // [512][1536]
    const float* Wout = (const float*)d_in[2];   // [512][512]
    const float* bout = (const float*)d_in[3];   // [512]
    float* out = (float*)d_out;                  // [16384][512] f32

    char* ws = (char*)d_ws;
    short* qkvb  = (short*)(ws);                 // 48 MB  [16384][1536] bf16
    short* xb    = (short*)(ws + 50331648ull);   // 16 MB  [16384][512]  bf16 (x)
    short* attnb = xb;                           // reuse: xb dead before attn writes
    short* Wqkvt = (short*)(ws + 67108864ull);   // 1.5 MB [1536][512]   bf16
    short* Woutt = (short*)(ws + 68681728ull);   // 0.5 MB [512][512]    bf16

    cvt_x<<<4096, 256, 0, stream>>>(x, xb);
    tr_w<<<768, 256, 0, stream>>>(Wqkv, Wqkvt, 512, 1536);   // 16 k-tiles x 48 n-tiles
    tr_w<<<256, 256, 0, stream>>>(Wout, Woutt, 512, 512);    // 16 x 16

    // M=16384 (128 mb) x N=1536 (12 nb) -> 1536 blocks (N fastest)
    gemm_db<0><<<1536, 256, 0, stream>>>(xb, Wqkvt, qkvb, nullptr, nullptr,
                                         16384, 1536, 512, 12);

    attn_kernel<<<1024, 512, 0, stream>>>(qkvb, attnb);

    // M=16384 (128 mb) x N=512 (4 nb) -> 512 blocks
    gemm_db<1><<<512, 256, 0, stream>>>(attnb, Woutt, nullptr, out, bout,
                                        16384, 512, 512, 4);
}

// Round 8
// 97.978 us; speedup vs baseline: 1.0557x; 1.0557x over previous
//
#include <hip/hip_runtime.h>
#include <hip/hip_bf16.h>

typedef short bf16x8 __attribute__((ext_vector_type(8)));
typedef short bf16x4 __attribute__((ext_vector_type(4)));
typedef float f32x4  __attribute__((ext_vector_type(4)));

__device__ __forceinline__ unsigned short f2bf(float f) {
    union { float fv; unsigned int u; } v; v.fv = f;
    unsigned int r = v.u + 0x7FFFu + ((v.u >> 16) & 1u);
    return (unsigned short)(r >> 16);
}

__device__ __forceinline__ short f2bf_n(float f) {
    union { __hip_bfloat16 h; short s; } u;
    u.h = __float2bfloat16(f);
    return u.s;
}

__device__ __forceinline__ void gload16(const short* g, short* l) {
    __builtin_amdgcn_global_load_lds(
        (const __attribute__((address_space(1))) void*)g,
        (__attribute__((address_space(3))) void*)l, 16, 0, 0);
}

// ---- convert x f32 -> bf16, 8 elems/thread ----
__global__ __launch_bounds__(256) void cvt_x(
    const float* __restrict__ x, short* __restrict__ xb)
{
    size_t i = ((size_t)blockIdx.x * 256 + threadIdx.x) * 8;
    f32x4 a = *(const f32x4*)(x + i);
    f32x4 b = *(const f32x4*)(x + i + 4);
    bf16x8 s;
    #pragma unroll
    for (int e = 0; e < 4; ++e) { s[e] = (short)f2bf(a[e]); s[4 + e] = (short)f2bf(b[e]); }
    *(bf16x8*)(xb + i) = s;
}

// ---- tiled transpose (both weights in one launch): f32 [K][N] -> bf16 [N][K]
__global__ __launch_bounds__(256) void tr_w2(
    const float* __restrict__ Wqkv, const float* __restrict__ Wout,
    short* __restrict__ Wqkvt, short* __restrict__ Woutt)
{
    __shared__ float tile[32][33];
    const int b = blockIdx.x;
    const float* src; short* dst; int N, bb;
    if (b < 768) { src = Wqkv; dst = Wqkvt; N = 1536; bb = b; }
    else         { src = Wout; dst = Woutt; N = 512;  bb = b - 768; }
    const int tx = threadIdx.x;
    const int nb = N >> 5;
    const int k0 = (bb / nb) * 32;
    const int n0 = (bb % nb) * 32;
    const int r  = tx >> 3;
    const int c4 = (tx & 7) * 4;
    f32x4 v = *(const f32x4*)(src + (size_t)(k0 + r) * N + n0 + c4);
    #pragma unroll
    for (int e = 0; e < 4; ++e) tile[r][c4 + e] = v[e];
    __syncthreads();
    bf16x4 o;
    #pragma unroll
    for (int e = 0; e < 4; ++e) o[e] = (short)f2bf(tile[c4 + e][r]);
    *(bf16x4*)(dst + (size_t)(n0 + r) * 512 + k0 + c4) = o;
}

// ---- GEMM: 128x128 tile, double-buffered LDS, counted vmcnt prefetch ----
template<int F32OUT>
__global__ __launch_bounds__(256, 2) void gemm_db(
    const short* __restrict__ A, const short* __restrict__ Bt,
    short* __restrict__ Cb, float* __restrict__ Cf, const float* __restrict__ bias,
    int M, int N, int K, int NB)
{
    __shared__ short lds[2][2][128 * 64];   // [buf][A|B][row*64+chunk*8]
    const int t    = threadIdx.x;
    const int lane = t & 63;
    const int wid  = t >> 6;
    const int l15  = lane & 15;
    const int lg   = lane >> 4;

    const int cpx = gridDim.x >> 3;
    const int swz = (blockIdx.x & 7) * cpx + (blockIdx.x >> 3);
    const int m0 = (swz / NB) * 128;
    const int n0 = (swz % NB) * 128;

    const int wm = (wid >> 1) * 64;
    const int wn = (wid & 1) * 64;

    const int scol = 8 * ((lane & 7) ^ ((lane >> 3) & 7));

    float bval[4];
    if constexpr (F32OUT) {
        #pragma unroll
        for (int ni = 0; ni < 4; ++ni) bval[ni] = bias[n0 + wn + ni * 16 + l15];
    }

    f32x4 acc[4][4];
    #pragma unroll
    for (int i = 0; i < 4; ++i)
        #pragma unroll
        for (int j = 0; j < 4; ++j)
            acc[i][j] = f32x4{0.f, 0.f, 0.f, 0.f};

    const int NT = K >> 6;

    auto stage = [&](int buf, int tk) {
        #pragma unroll
        for (int j = 0; j < 4; ++j) {
            const int r = wid * 32 + j * 8 + (lane >> 3);
            gload16(A  + (size_t)(m0 + r) * K + tk * 64 + scol,
                    &lds[buf][0][(wid * 32 + j * 8) * 64]);
            gload16(Bt + (size_t)(n0 + r) * K + tk * 64 + scol,
                    &lds[buf][1][(wid * 32 + j * 8) * 64]);
        }
    };

    stage(0, 0);

    for (int tk = 0; tk < NT; ++tk) {
        const int cur = tk & 1;
        if (tk + 1 < NT) {
            stage(cur ^ 1, tk + 1);
            asm volatile("s_waitcnt vmcnt(8)" ::: "memory");
        } else {
            asm volatile("s_waitcnt vmcnt(0)" ::: "memory");
        }
        __builtin_amdgcn_s_barrier();

        bf16x8 af[4][2], bg[4][2];
        #pragma unroll
        for (int kk = 0; kk < 2; ++kk) {
            #pragma unroll
            for (int mi = 0; mi < 4; ++mi)
                af[mi][kk] = *(const bf16x8*)&lds[cur][0][
                    (wm + mi * 16 + l15) * 64 + (((kk * 4 + lg) ^ (l15 & 7)) * 8)];
            #pragma unroll
            for (int ni = 0; ni < 4; ++ni)
                bg[ni][kk] = *(const bf16x8*)&lds[cur][1][
                    (wn + ni * 16 + l15) * 64 + (((kk * 4 + lg) ^ (l15 & 7)) * 8)];
        }

        __builtin_amdgcn_s_setprio(1);
        #pragma unroll
        for (int kk = 0; kk < 2; ++kk)
            #pragma unroll
            for (int mi = 0; mi < 4; ++mi)
                #pragma unroll
                for (int ni = 0; ni < 4; ++ni)
                    acc[mi][ni] = __builtin_amdgcn_mfma_f32_16x16x32_bf16(
                        af[mi][kk], bg[ni][kk], acc[mi][ni], 0, 0, 0);
        __builtin_amdgcn_s_setprio(0);
        __builtin_amdgcn_s_barrier();
    }

    #pragma unroll
    for (int mi = 0; mi < 4; ++mi) {
        #pragma unroll
        for (int ni = 0; ni < 4; ++ni) {
            const int col = n0 + wn + ni * 16 + l15;
            #pragma unroll
            for (int r = 0; r < 4; ++r) {
                const int rowi = m0 + wm + mi * 16 + 4 * lg + r;
                if constexpr (F32OUT) {
                    Cf[(size_t)rowi * N + col] = acc[mi][ni][r] + bval[ni];
                } else {
                    Cb[(size_t)rowi * N + col] = (short)f2bf(acc[mi][ni][r]);
                }
            }
        }
    }
}

// ---- fused attention: grid 512; block = (qhalf, bp, h); 8 waves x 32 q-rows
// K: global_load_lds direct, chunk-XOR swizzle (slot s holds chunk s^(row&7)),
//    double-buffered, gload issued AFTER the barrier into the idle buffer.
// V: reg-staged transpose into Vt[d][kv'], stride 80, octet swizzle
//    kv' = (kv&7) | 8*((kv>>3)^(d>>3))  -> conflict-free scalar writes.
// ONE __syncthreads per tile.
__global__ __launch_bounds__(512, 4) void attn_kernel(
    const short* __restrict__ qkv, short* __restrict__ attn_out)
{
    __shared__ short Kl[2][4096];    // [kv][64] linear, chunk-swizzled
    __shared__ short Vt[2][5120];    // [d][80] octet-swizzled
    const int t    = threadIdx.x;
    const int lane = t & 63;
    const int wid  = t >> 6;
    const int l15  = lane & 15;
    const int lg   = lane >> 4;
    const int pairid = blockIdx.x & 255;
    const int qh  = blockIdx.x >> 8;
    const int bp  = pairid >> 3;
    const int h   = pairid & 7;
    const size_t tok0 = (size_t)bp * 512;
    const int q0   = qh * 256 + wid * 32;
    const int qcol = h * 64;

    // Q fragments (B-operand layout): col m = l15, k(d) = kf*32 + 8*lg + e
    bf16x8 qf[2][2];
    #pragma unroll
    for (int mj = 0; mj < 2; ++mj)
        #pragma unroll
        for (int kf = 0; kf < 2; ++kf)
            qf[mj][kf] = *(const bf16x8*)(qkv + (tok0 + q0 + mj * 16 + l15) * 1536
                                          + qcol + kf * 32 + 8 * lg);

    f32x4 ot[4][2];
    #pragma unroll
    for (int i = 0; i < 4; ++i)
        #pragma unroll
        for (int j = 0; j < 2; ++j)
            ot[i][j] = f32x4{0.f, 0.f, 0.f, 0.f};
    float mrun[2] = {-1e30f, -1e30f}, lrun[2] = {0.f, 0.f};

    // K staging: thread t -> row t>>3, slot-chunk t&7 (16B each), source
    // chunk pre-swizzled: (t&7) ^ (row&7)
    const int krow = t >> 3;
    const short* Ksrc0 = qkv + (tok0 + krow) * 1536 + 512 + qcol
                         + 8 * ((t & 7) ^ (krow & 7));
    // V staging: thread t holds V[kv=sn][d = sd..sd+7]
    const int sn = t >> 3;
    const int sd = (t & 7) * 8;
    const short* Vsrc0 = qkv + (tok0 + sn) * 1536 + 1024 + qcol + sd;
    const int kvp = (sn & 7) | (((sn >> 3) ^ (t & 7)) << 3);   // swizzled col

    gload16(Ksrc0, &Kl[0][t * 8]);
    bf16x8 vreg = *(const bf16x8*)(Vsrc0);

    const float C = 0.18033688011112042f;   // 0.125 * log2(e)

    for (int tkv = 0; tkv < 8; ++tkv) {
        const int cur = tkv & 1;
        // write V^T tile (register wait on vreg also guarantees K[cur] landed)
        #pragma unroll
        for (int i = 0; i < 8; ++i)
            Vt[cur][(sd + i) * 80 + kvp] = vreg[i];
        __syncthreads();
        // prefetch next tile into the idle buffer (post-barrier: race-free)
        if (tkv < 7) {
            gload16(Ksrc0 + (size_t)(tkv + 1) * 64 * 1536, &Kl[cur ^ 1][t * 8]);
            vreg = *(const bf16x8*)(Vsrc0 + (size_t)(tkv + 1) * 64 * 1536);
        }

        // S^T = K * Q^T  (col m = l15, row n = ni*16 + 4*lg + r), raw scores
        f32x4 st[4][2];
        #pragma unroll
        for (int i = 0; i < 4; ++i)
            #pragma unroll
            for (int j = 0; j < 2; ++j)
                st[i][j] = f32x4{0.f, 0.f, 0.f, 0.f};
        __builtin_amdgcn_s_setprio(1);
        #pragma unroll
        for (int kf = 0; kf < 2; ++kf) {
            #pragma unroll
            for (int ni = 0; ni < 4; ++ni) {
                bf16x8 kfr = *(const bf16x8*)&Kl[cur][
                    (ni * 16 + l15) * 64 + (((kf * 4 + lg) ^ (l15 & 7)) * 8)];
                #pragma unroll
                for (int mj = 0; mj < 2; ++mj)
                    st[ni][mj] = __builtin_amdgcn_mfma_f32_16x16x32_bf16(
                        kfr, qf[mj][kf], st[ni][mj], 0, 0, 0);
            }
        }
        __builtin_amdgcn_s_setprio(0);

        // online softmax (log2 domain); fmax raw, scale once; defer-max THR=8
        #pragma unroll
        for (int mj = 0; mj < 2; ++mj) {
            float pm = -1e30f;
            #pragma unroll
            for (int ni = 0; ni < 4; ++ni)
                #pragma unroll
                for (int r = 0; r < 4; ++r)
                    pm = fmaxf(pm, st[ni][mj][r]);
            pm = fmaxf(pm, __shfl_xor(pm, 16));
            pm = fmaxf(pm, __shfl_xor(pm, 32));
            pm *= C;
            if (!__all(pm <= mrun[mj] + 8.f)) {
                const float mnew = fmaxf(mrun[mj], pm);
                const float fsc  = __builtin_amdgcn_exp2f(mrun[mj] - mnew);
                lrun[mj] *= fsc;
                #pragma unroll
                for (int di = 0; di < 4; ++di) ot[di][mj] *= fsc;
                mrun[mj] = mnew;
            }
            float ps = 0.f;
            #pragma unroll
            for (int ni = 0; ni < 4; ++ni)
                #pragma unroll
                for (int r = 0; r < 4; ++r) {
                    float e = __builtin_amdgcn_exp2f(
                        __builtin_fmaf(st[ni][mj][r], C, -mrun[mj]));
                    st[ni][mj][r] = e;
                    ps += e;
                }
            ps += __shfl_xor(ps, 16);
            ps += __shfl_xor(ps, 32);
            lrun[mj] += ps;
        }

        // O^T += V^T * P^T  (P^T D-frag is the 16x16x16 B-operand layout)
        __builtin_amdgcn_s_setprio(1);
        #pragma unroll
        for (int ni = 0; ni < 4; ++ni) {
            bf16x4 pb[2];
            #pragma unroll
            for (int mj = 0; mj < 2; ++mj)
                #pragma unroll
                for (int r = 0; r < 4; ++r)
                    pb[mj][r] = f2bf_n(st[ni][mj][r]);
            #pragma unroll
            for (int di = 0; di < 4; ++di) {
                const int row = di * 16 + l15;
                bf16x4 av = *(const bf16x4*)&Vt[cur][
                    row * 80
                    + (((2 * ni + (lg >> 1)) ^ (2 * di + (l15 >> 3))) * 8)
                    + 4 * (lg & 1)];
                #pragma unroll
                for (int mj = 0; mj < 2; ++mj)
                    ot[di][mj] = __builtin_amdgcn_mfma_f32_16x16x16bf16_1k(
                        av, pb[mj], ot[di][mj], 0, 0, 0);
            }
        }
        __builtin_amdgcn_s_setprio(0);
    }

    float inv[2];
    #pragma unroll
    for (int mj = 0; mj < 2; ++mj) inv[mj] = 1.f / lrun[mj];
    #pragma unroll
    for (int di = 0; di < 4; ++di)
        #pragma unroll
        for (int mj = 0; mj < 2; ++mj) {
            const size_t tok = tok0 + q0 + mj * 16 + l15;
            const int col = qcol + di * 16 + 4 * lg;
            bf16x4 o4;
            #pragma unroll
            for (int r = 0; r < 4; ++r)
                o4[r] = f2bf_n(ot[di][mj][r] * inv[mj]);
            *(bf16x4*)(attn_out + tok * 512 + col) = o4;
        }
}

extern "C" void kernel_launch(void* const* d_in, const int* in_sizes, int n_in,
                              void* d_out, int out_size, void* d_ws, size_t ws_size,
                              hipStream_t stream) {
    const float* x    = (const float*)d_in[0];   // [16384][512]
    const float* Wqkv = (const float*)d_in[1];   // [512][1536]
    const float* Wout = (const float*)d_in[2];   // [512][512]
    const float* bout = (const float*)d_in[3];   // [512]
    float* out = (float*)d_out;                  // [16384][512] f32

    char* ws = (char*)d_ws;
    short* qkvb  = (short*)(ws);                 // 48 MB  [16384][1536] bf16
    short* xb    = (short*)(ws + 50331648ull);   // 16 MB  [16384][512]  bf16 (x)
    short* attnb = xb;                           // reuse: xb dead before attn writes
    short* Wqkvt = (short*)(ws + 67108864ull);   // 1.5 MB [1536][512]   bf16
    short* Woutt = (short*)(ws + 68681728ull);   // 0.5 MB [512][512]    bf16

    cvt_x<<<4096, 256, 0, stream>>>(x, xb);
    tr_w2<<<1024, 256, 0, stream>>>(Wqkv, Wout, Wqkvt, Woutt);

    // M=16384 (128 mb) x N=1536 (12 nb) -> 1536 blocks (N fastest)
    gemm_db<0><<<1536, 256, 0, stream>>>(xb, Wqkvt, qkvb, nullptr, nullptr,
                                         16384, 1536, 512, 12);

    attn_kernel<<<512, 512, 0, stream>>>(qkvb, attnb);

    // M=16384 (128 mb) x N=512 (4 nb) -> 512 blocks
    gemm_db<1><<<512, 256, 0, stream>>>(attnb, Woutt, nullptr, out, bout,
                                        16384, 512, 512, 4);
}